// Round 1
// baseline (247.568 us; speedup 1.0000x reference)
//
#include <hip/hip_runtime.h>

#define COLS    32768
#define KSEL    32
#define CAP     2048      // candidate buffer (expected ~746 hits/row at BAR=2.0)
#define REF_CAP 256       // refined buffer after histogram prune (expected ~34)
#define NT      256
#define BAR     2.0f

// key = (float_bits << 32) | (0xFFFF - idx)
// positive float bits are monotonic in value; low 16 bits break ties so that
// larger key == (larger value, or equal value with smaller index) — matching
// jax.lax.top_k tie order. All keys distinct since idx distinct.

__global__ __launch_bounds__(NT) void topk_scatter_kernel(const float* __restrict__ x,
                                                          float* __restrict__ out) {
    __shared__ unsigned long long cand[CAP];
    __shared__ unsigned long long refbuf[REF_CAP];
    __shared__ unsigned hist[256];
    __shared__ int s_cnt, s_bstar, s_rcnt, s_cum;

    const int tid = threadIdx.x;
    const size_t row = blockIdx.x;
    const float* __restrict__ xr = x + row * COLS;
    float* __restrict__ outr = out + row * COLS;

    if (tid == 0) { s_cnt = 0; s_rcnt = 0; }
    __syncthreads();

    // ---- Pass 1: stream row (read x, write zeros, collect candidates > BAR) ----
    const float4* __restrict__ xr4 = (const float4*)xr;
    float4* __restrict__ our4 = (float4*)outr;
    const float4 z4 = make_float4(0.f, 0.f, 0.f, 0.f);

#pragma unroll 4
    for (int i = 0; i < COLS / 4 / NT; ++i) {
        const int e = i * NT + tid;
        float4 v = xr4[e];
        our4[e] = z4;
        const int base = e * 4;
        if (v.x > BAR) { int p = atomicAdd(&s_cnt, 1); if (p < CAP) cand[p] = ((unsigned long long)__float_as_uint(v.x) << 32) | (unsigned)(0xFFFF - (base + 0)); }
        if (v.y > BAR) { int p = atomicAdd(&s_cnt, 1); if (p < CAP) cand[p] = ((unsigned long long)__float_as_uint(v.y) << 32) | (unsigned)(0xFFFF - (base + 1)); }
        if (v.z > BAR) { int p = atomicAdd(&s_cnt, 1); if (p < CAP) cand[p] = ((unsigned long long)__float_as_uint(v.z) << 32) | (unsigned)(0xFFFF - (base + 2)); }
        if (v.w > BAR) { int p = atomicAdd(&s_cnt, 1); if (p < CAP) cand[p] = ((unsigned long long)__float_as_uint(v.w) << 32) | (unsigned)(0xFFFF - (base + 3)); }
    }
    __syncthreads();
    const int N = s_cnt;

    if (N >= KSEL && N <= CAP) {
        // ---- common path: histogram-prune candidates, then rank-select top-K ----
        for (int b = tid; b < 256; b += NT) hist[b] = 0;
        __syncthreads();
        for (int c = tid; c < N; c += NT) {
            unsigned bits = (unsigned)(cand[c] >> 32);
            unsigned b16 = (bits >> 16) - 0x4000u;   // bits >= 0x40000000 since v > 2.0
            if (b16 > 255u) b16 = 255u;              // saturate (keeps monotonicity)
            atomicAdd(&hist[b16], 1u);
        }
        __syncthreads();
        if (tid == 0) {
            int cum = 0, b = 255;
            for (; b >= 0; --b) { cum += (int)hist[b]; if (cum >= KSEL) break; }
            s_bstar = b;   // b >= 0 guaranteed (N >= KSEL)
        }
        __syncthreads();
        const int bstar = s_bstar;
        for (int c = tid; c < N; c += NT) {
            const unsigned long long kc = cand[c];
            unsigned bits = (unsigned)(kc >> 32);
            unsigned b16 = (bits >> 16) - 0x4000u;
            if (b16 > 255u) b16 = 255u;
            if ((int)b16 >= bstar) { int p = atomicAdd(&s_rcnt, 1); if (p < REF_CAP) refbuf[p] = kc; }
        }
        __syncthreads();
        const int M = s_rcnt;
        if (M <= REF_CAP) {
            for (int c = tid; c < M; c += NT) {
                const unsigned long long kc = refbuf[c];
                int rank = 0;
                for (int j = 0; j < M; ++j) rank += (refbuf[j] > kc) ? 1 : 0;
                if (rank < KSEL)
                    outr[0xFFFF - (int)(kc & 0xFFFFu)] = __uint_as_float((unsigned)(kc >> 32));
            }
        } else {
            // refine overflow (mass ties) — exact rank over full candidate list
            for (int c = tid; c < N; c += NT) {
                const unsigned long long kc = cand[c];
                int rank = 0;
                for (int j = 0; j < N; ++j) rank += (cand[j] > kc) ? 1 : 0;
                if (rank < KSEL)
                    outr[0xFFFF - (int)(kc & 0xFFFFu)] = __uint_as_float((unsigned)(kc >> 32));
            }
        }
        return;
    }

    // ---- exact fallback (should not trigger on N(0,1) data): radix select ----
    // Finds bit-threshold thr such that count{x>0, bits>=thr} in [K, CAP]
    // (or thr=1 if fewer than K positives), re-reading the (L2-hot) row.
    unsigned pref = 0, thr = 1;
    int need = KSEL, above = 0;
    for (int s = 24; s >= 0; s -= 8) {
        __syncthreads();
        for (int b = tid; b < 256; b += NT) hist[b] = 0;
        __syncthreads();
        for (int i = tid; i < COLS; i += NT) {
            float v = xr[i];
            if (v > 0.f) {
                unsigned bits = __float_as_uint(v);
                if (s == 24 || (bits >> (s + 8)) == pref)
                    atomicAdd(&hist[(bits >> s) & 255u], 1u);
            }
        }
        __syncthreads();
        if (tid == 0) {
            int cum = 0, b = 255;
            for (; b >= 0; --b) { if (cum + (int)hist[b] >= need) break; cum += (int)hist[b]; }
            s_bstar = b; s_cum = cum;
        }
        __syncthreads();
        const int b = s_bstar, cum = s_cum;
        if (b < 0) { thr = 1; break; }    // fewer than K positives: take all positives
        above += cum;
        need -= cum;
        pref = (pref << 8) | (unsigned)b;
        thr = pref << s;
        const int total = above + (int)hist[b];
        if (total <= CAP || s == 0) break;
    }
    __syncthreads();
    if (tid == 0) s_cnt = 0;
    __syncthreads();
    for (int i = tid; i < COLS; i += NT) {
        float v = xr[i];
        if (v > 0.f) {
            unsigned bits = __float_as_uint(v);
            if (bits >= thr) {
                int p = atomicAdd(&s_cnt, 1);
                if (p < CAP) cand[p] = ((unsigned long long)bits << 32) | (unsigned)(0xFFFF - i);
            }
        }
    }
    __syncthreads();
    const int M2 = min(s_cnt, CAP);
    for (int c = tid; c < M2; c += NT) {
        const unsigned long long kc = cand[c];
        int rank = 0;
        for (int j = 0; j < M2; ++j) rank += (cand[j] > kc) ? 1 : 0;
        if (rank < KSEL)
            outr[0xFFFF - (int)(kc & 0xFFFFu)] = __uint_as_float((unsigned)(kc >> 32));
    }
}

extern "C" void kernel_launch(void* const* d_in, const int* in_sizes, int n_in,
                              void* d_out, int out_size, void* d_ws, size_t ws_size,
                              hipStream_t stream) {
    const float* x = (const float*)d_in[0];
    float* out = (float*)d_out;
    const int rows = in_sizes[0] / COLS;
    hipLaunchKernelGGL(topk_scatter_kernel, dim3(rows), dim3(NT), 0, stream, x, out);
}

// Round 2
// 220.784 us; speedup vs baseline: 1.1213x; 1.1213x over previous
//
#include <hip/hip_runtime.h>

#define COLS    32768
#define KSEL    32
#define CAP     1024      // candidate buffer (expected ~203 hits/row at BAR=2.5, 57 sigma margin)
#define REF_CAP 256       // refined buffer after histogram prune (expected ~34)
#define NT      256
#define BAR     2.5f

typedef float f32x4 __attribute__((ext_vector_type(4)));

// key = (float_bits << 32) | (0xFFFF - idx)
// positive float bits are monotonic in value; low 16 bits break ties so that
// larger key == (larger value, or equal value with smaller index) — matching
// jax.lax.top_k tie order. All keys distinct since idx distinct.
__device__ __forceinline__ unsigned long long mk_key(float v, int idx) {
    return ((unsigned long long)__float_as_uint(v) << 32) | (unsigned)(0xFFFF - idx);
}

__global__ __launch_bounds__(NT) void topk_scatter_kernel(const float* __restrict__ x,
                                                          float* __restrict__ out) {
    __shared__ unsigned long long cand[CAP];
    __shared__ unsigned long long refbuf[REF_CAP];
    __shared__ unsigned hist[256];
    __shared__ unsigned suf[256];
    __shared__ int s_cnt, s_bstar, s_rcnt, s_cum;

    const int tid = threadIdx.x;
    const int lane = tid & 63;
    const size_t row = blockIdx.x;
    const float* __restrict__ xr = x + row * COLS;
    float* __restrict__ outr = out + row * COLS;

    if (tid == 0) { s_cnt = 0; s_rcnt = 0; }
    __syncthreads();

    // ---- Pass 1: stream row (nt-read x, nt-write zeros, wave-aggregated candidate push) ----
    const f32x4* __restrict__ xr4 = (const f32x4*)xr;
    f32x4* __restrict__ our4 = (f32x4*)outr;

#pragma unroll 4
    for (int i = 0; i < COLS / 4 / NT; ++i) {
        const int e = i * NT + tid;
        f32x4 v = __builtin_nontemporal_load(xr4 + e);
        f32x4 z = 0;
        __builtin_nontemporal_store(z, our4 + e);

        const bool p0 = v.x > BAR, p1 = v.y > BAR, p2 = v.z > BAR, p3 = v.w > BAR;
        const unsigned long long m0 = __ballot(p0), m1 = __ballot(p1),
                                 m2 = __ballot(p2), m3 = __ballot(p3);
        const int c0 = __popcll(m0), c1 = __popcll(m1), c2 = __popcll(m2), c3 = __popcll(m3);
        const int tot = c0 + c1 + c2 + c3;
        int base = 0;
        if (lane == 0 && tot) base = atomicAdd(&s_cnt, tot);
        base = __shfl(base, 0, 64);
        const unsigned long long lt = (1ull << lane) - 1;
        const int bi = e * 4;
        if (p0) { int p = base + __popcll(m0 & lt);                if (p < CAP) cand[p] = mk_key(v.x, bi + 0); }
        if (p1) { int p = base + c0 + __popcll(m1 & lt);           if (p < CAP) cand[p] = mk_key(v.y, bi + 1); }
        if (p2) { int p = base + c0 + c1 + __popcll(m2 & lt);      if (p < CAP) cand[p] = mk_key(v.z, bi + 2); }
        if (p3) { int p = base + c0 + c1 + c2 + __popcll(m3 & lt); if (p < CAP) cand[p] = mk_key(v.w, bi + 3); }
    }
    __syncthreads();
    const int N = s_cnt;

    if (N >= KSEL && N <= CAP) {
        // ---- common path: histogram-prune candidates, then rank-select top-K ----
        hist[tid] = 0;
        __syncthreads();
        for (int c = tid; c < N; c += NT) {
            unsigned bits = (unsigned)(cand[c] >> 32);
            unsigned b16 = (bits >> 16) - 0x4000u;   // bits >= 0x40200000 since v > 2.5
            if (b16 > 255u) b16 = 255u;              // saturate (keeps monotonicity)
            atomicAdd(&hist[b16], 1u);
        }
        __syncthreads();
        // parallel suffix-scan over 256 bins: suf[b] = sum_{j>=b} hist[j]
        suf[tid] = hist[tid];
        __syncthreads();
#pragma unroll
        for (int off = 1; off < 256; off <<= 1) {
            unsigned add = (tid + off < 256) ? suf[tid + off] : 0u;
            __syncthreads();
            suf[tid] += add;
            __syncthreads();
        }
        if (suf[tid] >= KSEL && (tid == 255 || suf[tid + 1] < KSEL)) s_bstar = tid;
        __syncthreads();
        const int bstar = s_bstar;
        for (int c = tid; c < N; c += NT) {
            const unsigned long long kc = cand[c];
            unsigned bits = (unsigned)(kc >> 32);
            unsigned b16 = (bits >> 16) - 0x4000u;
            if (b16 > 255u) b16 = 255u;
            if ((int)b16 >= bstar) { int p = atomicAdd(&s_rcnt, 1); if (p < REF_CAP) refbuf[p] = kc; }
        }
        __syncthreads();
        const int M = s_rcnt;
        if (M <= REF_CAP) {
            for (int c = tid; c < M; c += NT) {
                const unsigned long long kc = refbuf[c];
                int rank = 0;
                for (int j = 0; j < M; ++j) rank += (refbuf[j] > kc) ? 1 : 0;
                if (rank < KSEL)
                    outr[0xFFFF - (int)(kc & 0xFFFFu)] = __uint_as_float((unsigned)(kc >> 32));
            }
        } else {
            // refine overflow (mass ties) — exact rank over full candidate list
            for (int c = tid; c < N; c += NT) {
                const unsigned long long kc = cand[c];
                int rank = 0;
                for (int j = 0; j < N; ++j) rank += (cand[j] > kc) ? 1 : 0;
                if (rank < KSEL)
                    outr[0xFFFF - (int)(kc & 0xFFFFu)] = __uint_as_float((unsigned)(kc >> 32));
            }
        }
        return;
    }

    // ---- exact fallback (should not trigger on N(0,1) data): radix select ----
    // Finds bit-threshold thr such that count{x>0, bits>=thr} in [K, CAP]
    // (or thr=1 if fewer than K positives), re-reading the row.
    unsigned pref = 0, thr = 1;
    int need = KSEL, above = 0;
    for (int s = 24; s >= 0; s -= 8) {
        __syncthreads();
        hist[tid] = 0;
        __syncthreads();
        for (int i = tid; i < COLS; i += NT) {
            float v = xr[i];
            if (v > 0.f) {
                unsigned bits = __float_as_uint(v);
                if (s == 24 || (bits >> (s + 8)) == pref)
                    atomicAdd(&hist[(bits >> s) & 255u], 1u);
            }
        }
        __syncthreads();
        if (tid == 0) {
            int cum = 0, b = 255;
            for (; b >= 0; --b) { if (cum + (int)hist[b] >= need) break; cum += (int)hist[b]; }
            s_bstar = b; s_cum = cum;
        }
        __syncthreads();
        const int b = s_bstar, cum = s_cum;
        if (b < 0) { thr = 1; break; }    // fewer than K positives: take all positives
        above += cum;
        need -= cum;
        pref = (pref << 8) | (unsigned)b;
        thr = pref << s;
        const int total = above + (int)hist[b];
        if (total <= CAP || s == 0) break;
    }
    __syncthreads();
    if (tid == 0) s_cnt = 0;
    __syncthreads();
    for (int i = tid; i < COLS; i += NT) {
        float v = xr[i];
        if (v > 0.f) {
            unsigned bits = __float_as_uint(v);
            if (bits >= thr) {
                int p = atomicAdd(&s_cnt, 1);
                if (p < CAP) cand[p] = ((unsigned long long)bits << 32) | (unsigned)(0xFFFF - i);
            }
        }
    }
    __syncthreads();
    const int M2 = min(s_cnt, CAP);
    for (int c = tid; c < M2; c += NT) {
        const unsigned long long kc = cand[c];
        int rank = 0;
        for (int j = 0; j < M2; ++j) rank += (cand[j] > kc) ? 1 : 0;
        if (rank < KSEL)
            outr[0xFFFF - (int)(kc & 0xFFFFu)] = __uint_as_float((unsigned)(kc >> 32));
    }
}

extern "C" void kernel_launch(void* const* d_in, const int* in_sizes, int n_in,
                              void* d_out, int out_size, void* d_ws, size_t ws_size,
                              hipStream_t stream) {
    const float* x = (const float*)d_in[0];
    float* out = (float*)d_out;
    const int rows = in_sizes[0] / COLS;
    hipLaunchKernelGGL(topk_scatter_kernel, dim3(rows), dim3(NT), 0, stream, x, out);
}